// Round 3
// baseline (552.644 us; speedup 1.0000x reference)
//
#include <hip/hip_runtime.h>

#define BSZ 8
#define LSEQ 8192
#define DDIM 256
#define CHUNK 8
#define WARM 48
#define STEPS (CHUNK + WARM)   // 56
#define CPB 16                 // chains per block

typedef float f32x4 __attribute__((ext_vector_type(4)));
typedef _Float16 h8 __attribute__((ext_vector_type(8)));
typedef _Float16 h4 __attribute__((ext_vector_type(4)));

// U layout: row-major rows, cols swizzled within each 64-block:
//   U[row*256 + cb*64 + l15*4 + ct] == logical U[row][cb*64 + ct*16 + l15]
// so a scan lane (q,l15) reads its 4 ct-values for one chain-row as ONE 8B load,
// and the gemm_u writer stores its C-fragment quad as ONE 8B store.

// ---------------- conversions (+ zero page) ----------------
__global__ void k_cvt_mats(const float* __restrict__ A, const float* __restrict__ B,
                           const float* __restrict__ C, _Float16* __restrict__ AhT,
                           _Float16* __restrict__ Bh, _Float16* __restrict__ Ch,
                           float* __restrict__ Zp) {
  int r = blockIdx.x, c = threadIdx.x;
  AhT[c * 256 + r] = (_Float16)A[r * 256 + c];
  Bh[r * 256 + c] = (_Float16)B[r * 256 + c];
  Ch[r * 256 + c] = (_Float16)C[r * 256 + c];
  if (r == 0) Zp[c] = 0.f;  // 1KB zero page
}

// ---------------- U = x @ B^T ----------------
// 512 blocks x 128 rows. x staged once to LDS as fp16 (read 1x).
// Per wave: 32 rows; loop 4 col-blocks with bf regs reloaded per block (L2-hot).
__global__ __launch_bounds__(256, 2) void k_gemm_u(const float* __restrict__ x,
                                                   const _Float16* __restrict__ Bh,
                                                   _Float16* __restrict__ U) {
  __shared__ __align__(16) _Float16 xh[128][264];  // 264 pitch: 16B-aligned rows, 2-way banks
  const int tid = threadIdx.x, wv = tid >> 6, lane = tid & 63;
  const int l15 = lane & 15, q = lane >> 4;
  const size_t rowbase = (size_t)blockIdx.x * 128;
#pragma unroll
  for (int i = 0; i < 32; ++i) {
    const int f4 = i * 256 + tid;            // 8192 float4 = 128 rows x 256 cols
    const int row = f4 >> 6, c4 = f4 & 63;   // per wave: one full row per iter
    float4 v = *(const float4*)(x + (rowbase + row) * 256 + c4 * 4);
    h4 h;
    h[0] = (_Float16)v.x; h[1] = (_Float16)v.y; h[2] = (_Float16)v.z; h[3] = (_Float16)v.w;
    *(h4*)&xh[row][c4 * 4] = h;
  }
  __syncthreads();
#pragma unroll 1
  for (int cbk = 0; cbk < 4; ++cbk) {
    h8 bf[4][8];
#pragma unroll
    for (int ct = 0; ct < 4; ++ct)
#pragma unroll
      for (int kb = 0; kb < 8; ++kb)
        bf[ct][kb] = *(const h8*)(Bh + (size_t)(cbk * 64 + ct * 16 + l15) * 256 + kb * 32 + q * 8);
#pragma unroll
    for (int rt = 0; rt < 2; ++rt) {
      const int rloc = wv * 32 + rt * 16;
      f32x4 acc[4] = {};
#pragma unroll
      for (int kb = 0; kb < 8; ++kb) {
        h8 af = *(const h8*)&xh[rloc + l15][kb * 32 + q * 8];
#pragma unroll
        for (int ct = 0; ct < 4; ++ct)
          acc[ct] = __builtin_amdgcn_mfma_f32_16x16x32_f16(af, bf[ct][kb], acc[ct], 0, 0, 0);
      }
      const size_t grow = rowbase + rloc + q * 4;
#pragma unroll
      for (int r = 0; r < 4; ++r) {
        h4 hv;
        hv[0] = (_Float16)acc[0][r]; hv[1] = (_Float16)acc[1][r];
        hv[2] = (_Float16)acc[2][r]; hv[3] = (_Float16)acc[3][r];
        *(h4*)(U + (grow + r) * 256 + cbk * 64 + l15 * 4) = hv;  // swizzled layout
      }
    }
  }
}

// ---------------- fused MFMA scan + out-projection ----------------
// CHUNK=8: 8192 chains, 16/block, 512 blocks -> 2 independent barrier groups
// per CU (176 VGPR = 2 waves/SIMD). The serial per-step latency (~1700 cyc of
// barrier+ds+MFMA-chain+vmcnt) of one group is hidden by the other group's
// issue. Warm-up work grows 1.75x but MFMA/VALU issue was only ~45% of the
// step budget, so it rides inside the hidden latency.
__global__ __launch_bounds__(256, 2) void k_scan(const _Float16* __restrict__ U,
                                                 const _Float16* __restrict__ AhT,
                                                 const _Float16* __restrict__ Ch,
                                                 const _Float16* __restrict__ Zp,
                                                 float* __restrict__ O) {
  __shared__ __align__(16) _Float16 st[2][CPB][264];  // state dbuf, proven layout
  const int tid = threadIdx.x, wv = tid >> 6, lane = tid & 63;
  const int l15 = lane & 15, q = lane >> 4;
  const int cw = wv * 64;
  const int b = blockIdx.x >> 6;              // 64 blocks per batch (1024 chains)
  const int c0 = (blockIdx.x & 63) * CPB;
  const size_t bbase = (size_t)b * LSEQ;

  h8 bf[4][8], cf[4][8];
#pragma unroll
  for (int ct = 0; ct < 4; ++ct)
#pragma unroll
    for (int kb = 0; kb < 8; ++kb) {
      bf[ct][kb] = *(const h8*)(AhT + (size_t)(cw + ct * 16 + l15) * 256 + kb * 32 + q * 8);
      cf[ct][kb] = *(const h8*)(Ch + (size_t)(cw + ct * 16 + l15) * 256 + kb * 32 + q * 8);
    }

  for (int i = tid; i < CPB * 264; i += 256) ((_Float16*)st[0])[i] = (_Float16)0.f;

  // per-lane U fragment load for chain q*4+r at local time t (clamped to zero page)
  auto uload = [&](int t, int r) -> h4 {
    const int lr = (c0 + q * 4 + r) * CHUNK + t;
    const _Float16* p = (lr < 0 || lr >= LSEQ)
                            ? (Zp + l15 * 4)
                            : (U + (bbase + (size_t)lr) * 256 + cw + l15 * 4);
    return *(const h4*)p;
  };

  h4 up0 = uload(-WARM, 0), up1 = uload(-WARM, 1), up2 = uload(-WARM, 2), up3 = uload(-WARM, 3);
  __syncthreads();  // one full drain: zero-init + frag loads

  int cb = 0;
#pragma unroll 1
  for (int g = 0; g <= STEPS; ++g) {
    const int t = g - WARM;  // computes S_t (g<STEPS); emits O_{t-1} (t>=1)
    // prefetch next step's U fragments (overlaps this step's MFMA; never drained)
    h4 un0 = uload(t + 1, 0), un1 = uload(t + 1, 1), un2 = uload(t + 1, 2), un3 = uload(t + 1, 3);
    if (g < STEPS) {
      f32x4 acc[4];
#pragma unroll
      for (int ct = 0; ct < 4; ++ct) {
        acc[ct][0] = (float)up0[ct]; acc[ct][1] = (float)up1[ct];
        acc[ct][2] = (float)up2[ct]; acc[ct][3] = (float)up3[ct];
      }
      if (t >= 1) {
        f32x4 acc2[4] = {};
#pragma unroll
        for (int kb = 0; kb < 8; ++kb) {
          h8 af = *(const h8*)&st[cb][l15][kb * 32 + q * 8];
#pragma unroll
          for (int ct = 0; ct < 4; ++ct)
            acc[ct] = __builtin_amdgcn_mfma_f32_16x16x32_f16(af, bf[ct][kb], acc[ct], 0, 0, 0);
#pragma unroll
          for (int ct = 0; ct < 4; ++ct)
            acc2[ct] = __builtin_amdgcn_mfma_f32_16x16x32_f16(af, cf[ct][kb], acc2[ct], 0, 0, 0);
        }
#pragma unroll
        for (int ct = 0; ct < 4; ++ct)
#pragma unroll
          for (int r = 0; r < 4; ++r)
            st[cb ^ 1][q * 4 + r][cw + ct * 16 + l15] = (_Float16)acc[ct][r];
        const size_t orow = bbase + (size_t)(c0 + q * 4) * CHUNK + (t - 1);
#pragma unroll
        for (int ct = 0; ct < 4; ++ct)
#pragma unroll
          for (int r = 0; r < 4; ++r)
            O[(orow + (size_t)r * CHUNK) * 256 + cw + ct * 16 + l15] = acc2[ct][r];
      } else {
#pragma unroll
        for (int kb = 0; kb < 8; ++kb) {
          h8 af = *(const h8*)&st[cb][l15][kb * 32 + q * 8];
#pragma unroll
          for (int ct = 0; ct < 4; ++ct)
            acc[ct] = __builtin_amdgcn_mfma_f32_16x16x32_f16(af, bf[ct][kb], acc[ct], 0, 0, 0);
        }
#pragma unroll
        for (int ct = 0; ct < 4; ++ct)
#pragma unroll
          for (int r = 0; r < 4; ++r)
            st[cb ^ 1][q * 4 + r][cw + ct * 16 + l15] = (_Float16)acc[ct][r];
      }
    } else {  // g == STEPS: final O_{CHUNK-1} only
      f32x4 acc2[4] = {};
#pragma unroll
      for (int kb = 0; kb < 8; ++kb) {
        h8 af = *(const h8*)&st[cb][l15][kb * 32 + q * 8];
#pragma unroll
        for (int ct = 0; ct < 4; ++ct)
          acc2[ct] = __builtin_amdgcn_mfma_f32_16x16x32_f16(af, cf[ct][kb], acc2[ct], 0, 0, 0);
      }
      const size_t orow = bbase + (size_t)(c0 + q * 4) * CHUNK + (CHUNK - 1);
#pragma unroll
      for (int ct = 0; ct < 4; ++ct)
#pragma unroll
        for (int r = 0; r < 4; ++r)
          O[(orow + (size_t)r * CHUNK) * 256 + cw + ct * 16 + l15] = acc2[ct][r];
    }
    // cross-wave hazard is LDS-only (st dbuf): wait LDS, barrier — NO vmem drain
    asm volatile("s_waitcnt lgkmcnt(0)" ::: "memory");
    __builtin_amdgcn_s_barrier();
    asm volatile("" ::: "memory");
    up0 = un0; up1 = un1; up2 = un2; up3 = un3;
    cb ^= 1;
  }
}

extern "C" void kernel_launch(void* const* d_in, const int* in_sizes, int n_in,
                              void* d_out, int out_size, void* d_ws, size_t ws_size,
                              hipStream_t stream) {
  const float* x = (const float*)d_in[0];
  const float* A = (const float*)d_in[1];
  const float* B = (const float*)d_in[2];
  const float* C = (const float*)d_in[3];

  char* ws = (char*)d_ws;
  _Float16* U4 = (_Float16*)ws;                           // 33.5 MB (swizzled U)
  _Float16* AhT = (_Float16*)(ws + 33554432);             // 128 KB
  _Float16* Bh = (_Float16*)(ws + 33554432 + 131072);     // 128 KB
  _Float16* Ch = (_Float16*)(ws + 33554432 + 262144);     // 128 KB
  float* Zp = (float*)(ws + 33554432 + 393216);           // 1 KB zeros
  float* out = (float*)d_out;

  hipLaunchKernelGGL(k_cvt_mats, dim3(256), dim3(256), 0, stream, A, B, C, AhT, Bh, Ch, Zp);
  hipLaunchKernelGGL(k_gemm_u, dim3(512), dim3(256), 0, stream, x, Bh, U4);
  hipLaunchKernelGGL(k_scan, dim3(512), dim3(256), 0, stream, U4, AhT, Ch,
                     (const _Float16*)Zp, out);
}

// Round 4
// 184.232 us; speedup vs baseline: 2.9997x; 2.9997x over previous
//
#include <hip/hip_runtime.h>

#define BSZ 8
#define LSEQ 8192
#define DDIM 256
#define CHUNK 16
#define WARM 32
#define STEPS (CHUNK + WARM)   // 48
#define CPB 16                 // chains per block

typedef float f32x4 __attribute__((ext_vector_type(4)));
typedef _Float16 h8 __attribute__((ext_vector_type(8)));
typedef _Float16 h4 __attribute__((ext_vector_type(4)));
typedef _Float16 h2 __attribute__((ext_vector_type(2)));

// U layout: row-major rows, cols swizzled within each 64-block:
//   U[row*256 + g64*64 + l15*4 + ct] == logical U[row][g64*64 + ct*16 + l15]
// scan lane reads its 2 ct-values (ct-pair hf) for one chain-row as ONE 4B load;
// gemm_u writer stores its C-fragment quad as ONE 8B store.

// ---------------- conversions (+ zero page) ----------------
__global__ void k_cvt_mats(const float* __restrict__ A, const float* __restrict__ B,
                           const float* __restrict__ C, _Float16* __restrict__ AhT,
                           _Float16* __restrict__ Bh, _Float16* __restrict__ Ch,
                           float* __restrict__ Zp) {
  int r = blockIdx.x, c = threadIdx.x;
  AhT[c * 256 + r] = (_Float16)A[r * 256 + c];
  Bh[r * 256 + c] = (_Float16)B[r * 256 + c];
  Ch[r * 256 + c] = (_Float16)C[r * 256 + c];
  if (r == 0) Zp[c] = 0.f;  // 1KB zero page
}

// ---------------- U = x @ B^T ---------------- (proven R1 version, unchanged)
__global__ __launch_bounds__(256, 2) void k_gemm_u(const float* __restrict__ x,
                                                   const _Float16* __restrict__ Bh,
                                                   _Float16* __restrict__ U) {
  __shared__ __align__(16) _Float16 xh[128][264];
  const int tid = threadIdx.x, wv = tid >> 6, lane = tid & 63;
  const int l15 = lane & 15, q = lane >> 4;
  const size_t rowbase = (size_t)blockIdx.x * 128;
#pragma unroll
  for (int i = 0; i < 32; ++i) {
    const int f4 = i * 256 + tid;
    const int row = f4 >> 6, c4 = f4 & 63;
    float4 v = *(const float4*)(x + (rowbase + row) * 256 + c4 * 4);
    h4 h;
    h[0] = (_Float16)v.x; h[1] = (_Float16)v.y; h[2] = (_Float16)v.z; h[3] = (_Float16)v.w;
    *(h4*)&xh[row][c4 * 4] = h;
  }
  __syncthreads();
#pragma unroll 1
  for (int cbk = 0; cbk < 4; ++cbk) {
    h8 bf[4][8];
#pragma unroll
    for (int ct = 0; ct < 4; ++ct)
#pragma unroll
      for (int kb = 0; kb < 8; ++kb)
        bf[ct][kb] = *(const h8*)(Bh + (size_t)(cbk * 64 + ct * 16 + l15) * 256 + kb * 32 + q * 8);
#pragma unroll
    for (int rt = 0; rt < 2; ++rt) {
      const int rloc = wv * 32 + rt * 16;
      f32x4 acc[4] = {};
#pragma unroll
      for (int kb = 0; kb < 8; ++kb) {
        h8 af = *(const h8*)&xh[rloc + l15][kb * 32 + q * 8];
#pragma unroll
        for (int ct = 0; ct < 4; ++ct)
          acc[ct] = __builtin_amdgcn_mfma_f32_16x16x32_f16(af, bf[ct][kb], acc[ct], 0, 0, 0);
      }
      const size_t grow = rowbase + rloc + q * 4;
#pragma unroll
      for (int r = 0; r < 4; ++r) {
        h4 hv;
        hv[0] = (_Float16)acc[0][r]; hv[1] = (_Float16)acc[1][r];
        hv[2] = (_Float16)acc[2][r]; hv[3] = (_Float16)acc[3][r];
        *(h4*)(U + (grow + r) * 256 + cbk * 64 + l15 * 4) = hv;  // swizzled layout
      }
    }
  }
}

// ---------------- fused MFMA scan + out-projection ----------------
// Same 256-block / CHUNK=16 / 1-block-per-CU memory pattern as the proven R1
// kernel (FETCH ~39MB). Changes: (a) 8 waves x 32 cols -> fragment regs halve
// to 128 VGPR (R1's 176-VGPR cap forced per-step AhT/Ch reloads) and 2
// waves/SIMD overlap the serial ds/MFMA chain; (b) WARM 48->32 (0.8^32~8e-4,
// negligible vs fp16 error): 49 barrier steps instead of 65.
__global__ __launch_bounds__(512, 2) void k_scan(const _Float16* __restrict__ U,
                                                 const _Float16* __restrict__ AhT,
                                                 const _Float16* __restrict__ Ch,
                                                 const _Float16* __restrict__ Zp,
                                                 float* __restrict__ O) {
  __shared__ __align__(16) _Float16 st[2][CPB][264];  // state dbuf, proven layout
  const int tid = threadIdx.x, wv = tid >> 6, lane = tid & 63;
  const int l15 = lane & 15, q = lane >> 4;
  const int g64 = wv >> 1, hf = wv & 1;   // wave owns cols g64*64 + (2hf+ctl)*16 + l15
  const int b = blockIdx.x >> 5;
  const int c0 = (blockIdx.x & 31) * CPB;
  const size_t bbase = (size_t)b * LSEQ;

  h8 bf[2][8], cf[2][8];
#pragma unroll
  for (int ctl = 0; ctl < 2; ++ctl)
#pragma unroll
    for (int kb = 0; kb < 8; ++kb) {
      const size_t mo = (size_t)(g64 * 64 + (2 * hf + ctl) * 16 + l15) * 256 + kb * 32 + q * 8;
      bf[ctl][kb] = *(const h8*)(AhT + mo);
      cf[ctl][kb] = *(const h8*)(Ch + mo);
    }

  for (int i = tid; i < CPB * 264; i += 512) ((_Float16*)st[0])[i] = (_Float16)0.f;

  // per-lane U fragment load (2 ct-values, 4B) for chain q*4+r at local time t
  auto uload = [&](int t, int r) -> h2 {
    const int lr = (c0 + q * 4 + r) * CHUNK + t;
    const _Float16* p = (lr < 0 || lr >= LSEQ)
                            ? (Zp + l15 * 4 + 2 * hf)
                            : (U + (bbase + (size_t)lr) * 256 + g64 * 64 + l15 * 4 + 2 * hf);
    return *(const h2*)p;
  };

  // O running pointers: col base for ctl=0; ctl=1 is +16 floats
  float* op[4];
#pragma unroll
  for (int r = 0; r < 4; ++r)
    op[r] = O + (bbase + (size_t)(c0 + q * 4 + r) * CHUNK) * 256 + g64 * 64 + 2 * hf * 16 + l15;

  h2 up0 = uload(-WARM, 0), up1 = uload(-WARM, 1), up2 = uload(-WARM, 2), up3 = uload(-WARM, 3);
  __syncthreads();  // one full drain: zero-init + frag loads

  int cb = 0;
#pragma unroll 1
  for (int g = 0; g <= STEPS; ++g) {
    const int t = g - WARM;  // computes S_t (g<STEPS); emits O_{t-1} (t>=1)
    // prefetch next step's U fragments (overlaps this step's MFMA; never drained)
    h2 un0 = uload(t + 1, 0), un1 = uload(t + 1, 1), un2 = uload(t + 1, 2), un3 = uload(t + 1, 3);
    if (g < STEPS) {
      f32x4 acc[2];
#pragma unroll
      for (int ctl = 0; ctl < 2; ++ctl) {
        acc[ctl][0] = (float)up0[ctl]; acc[ctl][1] = (float)up1[ctl];
        acc[ctl][2] = (float)up2[ctl]; acc[ctl][3] = (float)up3[ctl];
      }
      if (t >= 1) {
        f32x4 acc2[2] = {};
#pragma unroll
        for (int kb = 0; kb < 8; ++kb) {
          h8 af = *(const h8*)&st[cb][l15][kb * 32 + q * 8];
#pragma unroll
          for (int ctl = 0; ctl < 2; ++ctl)
            acc[ctl] = __builtin_amdgcn_mfma_f32_16x16x32_f16(af, bf[ctl][kb], acc[ctl], 0, 0, 0);
#pragma unroll
          for (int ctl = 0; ctl < 2; ++ctl)
            acc2[ctl] = __builtin_amdgcn_mfma_f32_16x16x32_f16(af, cf[ctl][kb], acc2[ctl], 0, 0, 0);
        }
#pragma unroll
        for (int ctl = 0; ctl < 2; ++ctl)
#pragma unroll
          for (int r = 0; r < 4; ++r)
            st[cb ^ 1][q * 4 + r][g64 * 64 + (2 * hf + ctl) * 16 + l15] = (_Float16)acc[ctl][r];
#pragma unroll
        for (int r = 0; r < 4; ++r) {
          op[r][0] = acc2[0][r];
          op[r][16] = acc2[1][r];
          op[r] += 256;
        }
      } else {
#pragma unroll
        for (int kb = 0; kb < 8; ++kb) {
          h8 af = *(const h8*)&st[cb][l15][kb * 32 + q * 8];
#pragma unroll
          for (int ctl = 0; ctl < 2; ++ctl)
            acc[ctl] = __builtin_amdgcn_mfma_f32_16x16x32_f16(af, bf[ctl][kb], acc[ctl], 0, 0, 0);
        }
#pragma unroll
        for (int ctl = 0; ctl < 2; ++ctl)
#pragma unroll
          for (int r = 0; r < 4; ++r)
            st[cb ^ 1][q * 4 + r][g64 * 64 + (2 * hf + ctl) * 16 + l15] = (_Float16)acc[ctl][r];
      }
    } else {  // g == STEPS: final O_{CHUNK-1} only
      f32x4 acc2[2] = {};
#pragma unroll
      for (int kb = 0; kb < 8; ++kb) {
        h8 af = *(const h8*)&st[cb][l15][kb * 32 + q * 8];
#pragma unroll
        for (int ctl = 0; ctl < 2; ++ctl)
          acc2[ctl] = __builtin_amdgcn_mfma_f32_16x16x32_f16(af, cf[ctl][kb], acc2[ctl], 0, 0, 0);
      }
#pragma unroll
      for (int r = 0; r < 4; ++r) {
        op[r][0] = acc2[0][r];
        op[r][16] = acc2[1][r];
      }
    }
    // cross-wave hazard is LDS-only (st dbuf): wait LDS, barrier — NO vmem drain
    asm volatile("s_waitcnt lgkmcnt(0)" ::: "memory");
    __builtin_amdgcn_s_barrier();
    asm volatile("" ::: "memory");
    up0 = un0; up1 = un1; up2 = un2; up3 = un3;
    cb ^= 1;
  }
}

extern "C" void kernel_launch(void* const* d_in, const int* in_sizes, int n_in,
                              void* d_out, int out_size, void* d_ws, size_t ws_size,
                              hipStream_t stream) {
  const float* x = (const float*)d_in[0];
  const float* A = (const float*)d_in[1];
  const float* B = (const float*)d_in[2];
  const float* C = (const float*)d_in[3];

  char* ws = (char*)d_ws;
  _Float16* U4 = (_Float16*)ws;                           // 33.5 MB (swizzled U)
  _Float16* AhT = (_Float16*)(ws + 33554432);             // 128 KB
  _Float16* Bh = (_Float16*)(ws + 33554432 + 131072);     // 128 KB
  _Float16* Ch = (_Float16*)(ws + 33554432 + 262144);     // 128 KB
  float* Zp = (float*)(ws + 33554432 + 393216);           // 1 KB zeros
  float* out = (float*)d_out;

  hipLaunchKernelGGL(k_cvt_mats, dim3(256), dim3(256), 0, stream, A, B, C, AhT, Bh, Ch, Zp);
  hipLaunchKernelGGL(k_gemm_u, dim3(512), dim3(256), 0, stream, x, Bh, U4);
  hipLaunchKernelGGL(k_scan, dim3(256), dim3(512), 0, stream, U4, AhT, Ch,
                     (const _Float16*)Zp, out);
}